// Round 4
// baseline (358.521 us; speedup 1.0000x reference)
//
#include <hip/hip_runtime.h>

// DiscriminativeLoss — B=8, D=32, N=131072, K=64.
// R6: one-hot MFMA for the k1 scatter (segment sums).
// R9: k3 = LDS gather; musum via global fp32 atomics.
// R11: k1 x-staging through swizzled LDS tile (contiguous 1KB row reads) — 248.1us.
// R12: dispatch consolidation 5 -> 3 (the ~40us residual over the ~50us work
// model is per-dispatch overhead, not kernel inner loops):
//  (a) k0: ids from sem/inst AND zeroes musum/cnt/vsum/tickets/out in-kernel
//      -> both hipMemsetAsync dispatches gone (k0->k1 boundary = ordering).
//  (b) k1: reads id8 (1MB) instead of sem/inst (8.4MB); recounts s_cnt from id8.
//  (c) k3: absorbs k4 via per-batch last-block ticket (threadfence + relaxed
//      atomicAdd + threadfence — rocPRIM idiom); finisher block computes
//      dist/reg/var for its batch in LDS [64][33] (conflict-free pair loop)
//      and atomicAdds into k0-zeroed out. k4 dispatch gone.

typedef unsigned char uchar;
typedef __attribute__((ext_vector_type(8)))  short bf16x8;
typedef __attribute__((ext_vector_type(16))) float f32x16;

#define IGNORE_IDX (-100)

constexpr int B = 8;
constexpr int D = 32;
constexpr int K = 64;
constexpr int NPTS = 131072;
constexpr int BPB  = 128;              // blocks per batch
constexpr int SPAN = 1024;             // points per block
constexpr float DELTA_V = 0.5f;
constexpr float TWO_DELTA_D = 3.0f;
constexpr float PARAM_REG = 0.001f;

// ws float offsets: [musum B*2048][cnt B*64 int][vsum B*64][ticket 8 int][id8 B*N bytes]
constexpr size_t OFF_CNT = (size_t)B * 2048;          // 16384
constexpr size_t OFF_VS  = OFF_CNT + (size_t)B * K;   // 16896
constexpr size_t OFF_TK  = OFF_VS  + (size_t)B * K;   // 17408
constexpr size_t OFF_ID  = OFF_TK + 8;                // 17416 (x4B = 16B aligned)
constexpr int ZERO_FLOATS = 17416;                    // musum..tickets

// pack two pre-rounded fp32 bit patterns into a bf16 pair (1 v_perm_b32)
__device__ inline unsigned bfpack(unsigned a0, unsigned a1) {
    return __builtin_amdgcn_perm(a1, a0, 0x07060302u);   // [a0>>16 | (a1>>16)<<16]
}

// ---------------------------------------------------------------- K0: ids + ws zeroing
__global__ __launch_bounds__(256) void k0_ids(
    const int* __restrict__ sem, const int* __restrict__ inst,
    uchar* __restrict__ id8, float* __restrict__ zbuf, float* __restrict__ out)
{
    const int t = threadIdx.x, blk = blockIdx.x;
    const int zi = blk * 256 + t;
    if (zi < ZERO_FLOATS) zbuf[zi] = 0.f;          // musum | cnt | vsum | tickets
    if (blk == 100 && t < 4) out[t] = 0.f;

    const int base = blk * 2048 + t * 8;
    const int4 c0 = *(const int4*)(sem + base);
    const int4 c1 = *(const int4*)(sem + base + 4);
    const int4 i0 = *(const int4*)(inst + base);
    const int4 i1 = *(const int4*)(inst + base + 4);
    const int cl[8] = {c0.x, c0.y, c0.z, c0.w, c1.x, c1.y, c1.z, c1.w};
    const int il[8] = {i0.x, i0.y, i0.z, i0.w, i1.x, i1.y, i1.z, i1.w};

    unsigned w0 = 0, w1 = 0;
#pragma unroll
    for (int j = 0; j < 8; ++j) {
        const bool v = (cl[j] != IGNORE_IDX);
        int q = (cl[j] == 1) ? 0 : il[j];
        q = (q < 0) ? 0 : (q > K - 1 ? K - 1 : q);
        const unsigned byte = v ? (unsigned)q : 255u;
        if (j < 4) w0 |= byte << (8 * j);
        else       w1 |= byte << (8 * (j - 4));
    }
    *(uint2*)(id8 + base) = make_uint2(w0, w1);
}

// ---------------------------------------------------------------- K1: segment sums via MFMA onehot
// C[d=32][khalf=32] += A(x)[d][n=16] * B(onehot)[n][khalf]
// A: m=lane&31, kdim=(lane>>5)*8+j.  B: ncol=lane&31, kdim same.
// C: col=lane&31, row=(reg&3)+8*(reg>>2)+4*(lane>>5)  [m74/m101 verified].
__global__ __launch_bounds__(256) void k1_fused(
    const float* __restrict__ x, const uchar* __restrict__ id8,
    int* __restrict__ cnt, float* __restrict__ musum)
{
    // union: bf16 tile [32 rows][256 pts] (16KB, swizzled) during the loop;
    // s_part[4][2048] fp32 (32KB) in the epilogue only.
    __shared__ __align__(16) char s_mem[32768];
    __shared__ unsigned s_id4[256];
    __shared__ int s_cnt[K];
    const int t = threadIdx.x, w = t >> 6, L = t & 63;
    const int g = L >> 5, ln = L & 31;
    const unsigned lnu = (unsigned)ln, lnp32 = (unsigned)(ln + 32);
    const int blk = blockIdx.x, b = blk >> 7, sp = blk & (BPB - 1);

    if (t < K) s_cnt[t] = 0;
    __syncthreads();

    // ids for this span from k0's id8 (1 word = 4 pts per thread)
    {
        const size_t off = (size_t)b * NPTS + sp * SPAN + t * 4;
        const unsigned wrd = *(const unsigned*)(id8 + off);
        s_id4[t] = wrd;
#pragma unroll
        for (int j = 0; j < 4; ++j) {
            const unsigned e = (wrd >> (8 * j)) & 255u;
            if (e < 64u) atomicAdd(&s_cnt[e], 1);
        }
    }

    f32x16 acc0, acc1;
#pragma unroll
    for (int i = 0; i < 16; ++i) { acc0[i] = 0.f; acc1[i] = 0.f; }

    const unsigned* xb = (const unsigned*)(x + (size_t)b * D * NPTS + sp * SPAN);

    // prefetch subtile 0: wave w owns rows {w, 4+w, ..., 28+w}; 1KB contiguous per row
    uint4 pf[8];
#pragma unroll
    for (int P = 0; P < 8; ++P)
        pf[P] = *(const uint4*)(xb + (size_t)(P * 4 + w) * NPTS + L * 4);

    for (int st = 0; st < 4; ++st) {
        // ---- write prefetched tile -> LDS bf16, 16B-granule XOR swizzle
#pragma unroll
        for (int P = 0; P < 8; ++P) {
            const int row = P * 4 + w;
            const unsigned u0 = bfpack(pf[P].x + 0x8000u, pf[P].y + 0x8000u);
            const unsigned u1 = bfpack(pf[P].z + 0x8000u, pf[P].w + 0x8000u);
            const int waddr = row * 512 + (((L >> 1) ^ (row & 7)) * 16) + (L & 1) * 8;
            *(uint2*)(s_mem + waddr) = make_uint2(u0, u1);
        }
        if (st < 3) {                                  // prefetch next subtile
#pragma unroll
            for (int P = 0; P < 8; ++P)
                pf[P] = *(const uint4*)(xb + (size_t)(P * 4 + w) * NPTS
                                        + (st + 1) * 256 + L * 4);
        }
        __syncthreads();

        // ---- 4 chunks of 16 pts per wave
#pragma unroll
        for (int cc = 0; cc < 4; ++cc) {
            const int K16 = (w * 4 + cc) * 2 + g;      // 16B granule 0..31
            const int raddr = ln * 512 + ((K16 ^ (ln & 7)) * 16);
            const bf16x8 Af = *(const bf16x8*)(s_mem + raddr);

            const int n0 = st * 256 + (w * 4 + cc) * 16 + g * 8;
            const uint2 idq = *(const uint2*)(&s_id4[n0 >> 2]);
            union { unsigned u[4]; bf16x8 v; } B0, B1;
#pragma unroll
            for (int p = 0; p < 4; ++p) {
                const unsigned pair = ((p < 2) ? idq.x : idq.y) >> ((p & 1) * 16);
                const unsigned e0 = pair & 255u, e1 = (pair >> 8) & 255u;
                unsigned r0 = (e0 == lnu)   ? 0x3F80u : 0u;
                unsigned r1 = (e0 == lnp32) ? 0x3F80u : 0u;
                if (e1 == lnu)   r0 |= 0x3F800000u;
                if (e1 == lnp32) r1 |= 0x3F800000u;
                B0.u[p] = r0; B1.u[p] = r1;
            }
            acc0 = __builtin_amdgcn_mfma_f32_32x32x16_bf16(Af, B0.v, acc0, 0, 0, 0);
            acc1 = __builtin_amdgcn_mfma_f32_32x32x16_bf16(Af, B1.v, acc1, 0, 0, 0);
        }
        __syncthreads();
    }

    // ---- epilogue: combine 4 waves in LDS (reuse s_mem), atomics into musum
    float (*s_part)[2048] = (float(*)[2048])s_mem;
#pragma unroll
    for (int r = 0; r < 16; ++r) {
        const int row = (r & 3) + 8 * (r >> 2) + 4 * g;   // d
        s_part[w][row * 64 + ln]      = acc0[r];          // k = ln
        s_part[w][row * 64 + ln + 32] = acc1[r];          // k = ln+32
    }
    __syncthreads();

    float* dst = musum + (size_t)b * 2048;                // layout [d][k]
    for (int i = t; i < 2048; i += 256)
        unsafeAtomicAdd(&dst[i],
            s_part[0][i] + s_part[1][i] + s_part[2][i] + s_part[3][i]);
    if (t < K) {
        const int c = s_cnt[t];
        if (c) atomicAdd(&cnt[b * K + t], c);
    }
}

// ---------------------------------------------------------------- block reduce (256 thr)
__device__ float block_reduce_sum256(float v, float* s_buf) {
    for (int o = 32; o > 0; o >>= 1) v += __shfl_down(v, o, 64);
    const int wid  = threadIdx.x >> 6;
    const int lane = threadIdx.x & 63;
    if (lane == 0) s_buf[wid] = v;
    __syncthreads();
    float r = 0.f;
    if (threadIdx.x == 0)
        for (int w = 0; w < 4; ++w) r += s_buf[w];
    __syncthreads();
    return r;
}

// ---------------------------------------------------------------- K3: variance gather + ticketed finalize
__global__ __launch_bounds__(256) void k3_var(
    const float* __restrict__ x, const uchar* __restrict__ id8,
    const float* __restrict__ musum, const int* __restrict__ cnt,
    float* __restrict__ vsum, int* __restrict__ ticket, float* __restrict__ out)
{
    __shared__ float s_pool[2112];                 // s_mu[2048] | s_var[64]; finisher: [64][33]
    __shared__ float s_fc[K];
    __shared__ float s_red[4];
    __shared__ int   s_last;
    float* s_mu  = s_pool;
    float* s_var = s_pool + 2048;

    const int t = threadIdx.x;
    const int blk = blockIdx.x, b = blk >> 7, sp = blk & (BPB - 1);

    if (t < K) s_var[t] = 0.f;
    for (int i = t; i < 2048; i += 256)
        s_mu[i] = musum[(size_t)b * 2048 + i]
                / ((float)cnt[b * K + (i & 63)] + 1e-8f);

    const unsigned idw = *(const unsigned*)(id8 + (size_t)b * NPTS + sp * SPAN + t * 4);
    int q[4]; bool val[4];
#pragma unroll
    for (int j = 0; j < 4; ++j) {
        const unsigned e = (idw >> (8 * j)) & 255u;
        val[j] = (e < 64u);
        q[j] = (int)(e & 63u);          // clamped LDS index for invalid pts
    }
    __syncthreads();

    const float* xp = x + (size_t)b * D * NPTS + sp * SPAN + t * 4;
    float s0 = 0.f, s1 = 0.f, s2 = 0.f, s3 = 0.f;
#pragma unroll
    for (int d = 0; d < D; ++d) {
        const float4 xv = *(const float4*)(xp + (size_t)d * NPTS);
        s0 += fabsf(xv.x - s_mu[d * 64 + q[0]]);
        s1 += fabsf(xv.y - s_mu[d * 64 + q[1]]);
        s2 += fabsf(xv.z - s_mu[d * 64 + q[2]]);
        s3 += fabsf(xv.w - s_mu[d * 64 + q[3]]);
    }

    const float ss[4] = {s0, s1, s2, s3};
#pragma unroll
    for (int j = 0; j < 4; ++j) {
        if (val[j]) {
            const float h = fmaxf(ss[j] - DELTA_V, 0.f);
            if (h > 0.f) unsafeAtomicAdd(&s_var[q[j]], h * h);
        }
    }
    __syncthreads();
    if (t < K) {
        const float v = s_var[t];
        if (v != 0.f) unsafeAtomicAdd(&vsum[b * K + t], v);
    }

    // ---- per-batch ticket: last of the 128 blocks finalizes batch b
    __threadfence();
    __syncthreads();
    if (t == 0) s_last = (atomicAdd(&ticket[b], 1) == BPB - 1) ? 1 : 0;
    __syncthreads();
    if (!s_last) return;
    __threadfence();

    // finisher: mu -> s_pool as [k][33] (pair loop conflict-free: (j*33+d)&31=(j+d)&31)
    if (t < K) s_fc[t] = (float)cnt[b * K + t];
    __syncthreads();                                    // s_pool reuse barrier
    for (int i = t; i < 2048; i += 256) {
        const int d = i >> 6, k = i & 63;
        s_pool[k * 33 + d] = musum[(size_t)b * 2048 + i]
                           / ((float)cnt[b * K + k] + 1e-8f);
    }
    __syncthreads();

    float distPart = 0.f;
    for (int p = t; p < K * K; p += 256) {
        const int i = p >> 6, j = p & 63;
        if (i != j && s_fc[i] > 0.f && s_fc[j] > 0.f) {
            float dsum = 0.f;
#pragma unroll
            for (int d = 0; d < D; ++d)
                dsum += fabsf(s_pool[i * 33 + d] - s_pool[j * 33 + d]);
            const float h = fmaxf(TWO_DELTA_D - dsum, 0.f);
            distPart += h * h;
        }
    }
    float regPart = 0.f;
    for (int i = t; i < K * D; i += 256) {
        const int k = i >> 5;
        if (s_fc[k] > 0.f) regPart += fabsf(s_pool[k * 33 + (i & 31)]);
    }
    float varPart = 0.f, npPart = 0.f;
    if (t < K) {
        varPart = vsum[b * K + t] / (s_fc[t] + 1e-8f);
        npPart  = (s_fc[t] > 0.f) ? 1.f : 0.f;
    }

    const float distSum = block_reduce_sum256(distPart, s_red);
    const float regSum  = block_reduce_sum256(regPart,  s_red);
    const float varSum  = block_reduce_sum256(varPart,  s_red);
    const float npSum   = block_reduce_sum256(npPart,   s_red);

    if (t == 0) {
        const float n_inst = fmaxf(npSum, 1.0f);
        const float npairs = npSum * npSum - npSum;
        const float l_var  = varSum / n_inst;
        const float l_dist = (npairs > 0.f) ? (distSum / fmaxf(npairs, 1.0f)) : 0.f;
        const float l_reg  = PARAM_REG * (regSum / n_inst);
        const float invB   = 1.0f / (float)B;
        unsafeAtomicAdd(out + 0, (l_var + l_dist + l_reg) * invB);
        unsafeAtomicAdd(out + 1, l_var  * invB);
        unsafeAtomicAdd(out + 2, l_dist * invB);
        unsafeAtomicAdd(out + 3, l_reg  * invB);
    }
}

// ---------------------------------------------------------------- launch
extern "C" void kernel_launch(void* const* d_in, const int* in_sizes, int n_in,
                              void* d_out, int out_size, void* d_ws, size_t ws_size,
                              hipStream_t stream) {
    const float* x    = (const float*)d_in[0];
    const int*   sem  = (const int*)d_in[1];
    const int*   inst = (const int*)d_in[2];
    float*       out  = (float*)d_out;
    float*       ws   = (float*)d_ws;

    float* musum  = ws;
    int*   cnt    = (int*)(ws + OFF_CNT);
    float* vsum   = ws + OFF_VS;
    int*   ticket = (int*)(ws + OFF_TK);
    uchar* id8    = (uchar*)(ws + OFF_ID);

    k0_ids  <<<dim3(B * NPTS / 2048), dim3(256), 0, stream>>>(sem, inst, id8, ws, out);
    k1_fused<<<dim3(B * BPB), dim3(256), 0, stream>>>(x, id8, cnt, musum);
    k3_var  <<<dim3(B * BPB), dim3(256), 0, stream>>>(x, id8, musum, cnt, vsum, ticket, out);
}

// Round 5
// 245.953 us; speedup vs baseline: 1.4577x; 1.4577x over previous
//
#include <hip/hip_runtime.h>

// DiscriminativeLoss — B=8, D=32, N=131072, K=64.
// R6: one-hot MFMA for the k1 scatter (segment sums).
// R9: k3 = LDS gather; musum via global fp32 atomics.
// R11: k1 x-staging through swizzled LDS tile (contiguous 1KB row reads) — 248.1us.
// R12 (REVERTED): per-batch ticket finisher in k3 = +110us. Root cause: each
// __threadfence on gfx950 is an L2 writeback+invalidate (per-XCD L2s are
// non-coherent); 1024 blocks x 2 fences serialized at the TCC (k3: 22->166us,
// occupancy 15%, VALUBusy 2%). NEVER use per-block device fences / tickets /
// grid-sync on multi-XCD CDNA — dispatch boundaries ARE the cheap fence.
// R13: keep R12's fence-free wins only:
//  (a) k0: ids + zero ws scalars + out in-kernel -> both memset dispatches gone.
//  (b) k1 reads id8 (1MB) instead of sem/inst (8.4MB).
//  (c) k3/k4 = R11's verified forms. 4 dispatches: k0, k1, k3, k4.

typedef unsigned char uchar;
typedef __attribute__((ext_vector_type(8)))  short bf16x8;
typedef __attribute__((ext_vector_type(16))) float f32x16;

#define IGNORE_IDX (-100)

constexpr int B = 8;
constexpr int D = 32;
constexpr int K = 64;
constexpr int NPTS = 131072;
constexpr int BPB  = 128;              // blocks per batch
constexpr int SPAN = 1024;             // points per block
constexpr float DELTA_V = 0.5f;
constexpr float TWO_DELTA_D = 3.0f;
constexpr float PARAM_REG = 0.001f;

// ws float offsets: [musum B*2048][cnt B*64 int][vsum B*64][id8 B*N bytes]
constexpr size_t OFF_CNT = (size_t)B * 2048;          // 16384
constexpr size_t OFF_VS  = OFF_CNT + (size_t)B * K;   // 16896
constexpr size_t OFF_ID  = OFF_VS  + (size_t)B * K;   // 17408 (x4B -> 16B aligned)
constexpr int ZERO_FLOATS = 17408;                    // musum | cnt | vsum

// pack two pre-rounded fp32 bit patterns into a bf16 pair (1 v_perm_b32)
__device__ inline unsigned bfpack(unsigned a0, unsigned a1) {
    return __builtin_amdgcn_perm(a1, a0, 0x07060302u);   // [a0>>16 | (a1>>16)<<16]
}

// ---------------------------------------------------------------- K0: ids + ws zeroing
__global__ __launch_bounds__(256) void k0_ids(
    const int* __restrict__ sem, const int* __restrict__ inst,
    uchar* __restrict__ id8, float* __restrict__ zbuf, float* __restrict__ out)
{
    const int t = threadIdx.x, blk = blockIdx.x;
    const int zi = blk * 256 + t;
    if (zi < ZERO_FLOATS) zbuf[zi] = 0.f;          // musum | cnt | vsum
    if (blk == 100 && t < 4) out[t] = 0.f;

    const int base = blk * 2048 + t * 8;
    const int4 c0 = *(const int4*)(sem + base);
    const int4 c1 = *(const int4*)(sem + base + 4);
    const int4 i0 = *(const int4*)(inst + base);
    const int4 i1 = *(const int4*)(inst + base + 4);
    const int cl[8] = {c0.x, c0.y, c0.z, c0.w, c1.x, c1.y, c1.z, c1.w};
    const int il[8] = {i0.x, i0.y, i0.z, i0.w, i1.x, i1.y, i1.z, i1.w};

    unsigned w0 = 0, w1 = 0;
#pragma unroll
    for (int j = 0; j < 8; ++j) {
        const bool v = (cl[j] != IGNORE_IDX);
        int q = (cl[j] == 1) ? 0 : il[j];
        q = (q < 0) ? 0 : (q > K - 1 ? K - 1 : q);
        const unsigned byte = v ? (unsigned)q : 255u;
        if (j < 4) w0 |= byte << (8 * j);
        else       w1 |= byte << (8 * (j - 4));
    }
    *(uint2*)(id8 + base) = make_uint2(w0, w1);
}

// ---------------------------------------------------------------- K1: segment sums via MFMA onehot
// C[d=32][khalf=32] += A(x)[d][n=16] * B(onehot)[n][khalf]
// A: m=lane&31, kdim=(lane>>5)*8+j.  B: ncol=lane&31, kdim same.
// C: col=lane&31, row=(reg&3)+8*(reg>>2)+4*(lane>>5)  [m74/m101 verified].
__global__ __launch_bounds__(256) void k1_fused(
    const float* __restrict__ x, const uchar* __restrict__ id8,
    int* __restrict__ cnt, float* __restrict__ musum)
{
    // union: bf16 tile [32 rows][256 pts] (16KB, swizzled) during the loop;
    // s_part[4][2048] fp32 (32KB) in the epilogue only.
    __shared__ __align__(16) char s_mem[32768];
    __shared__ unsigned s_id4[256];
    __shared__ int s_cnt[K];
    const int t = threadIdx.x, w = t >> 6, L = t & 63;
    const int g = L >> 5, ln = L & 31;
    const unsigned lnu = (unsigned)ln, lnp32 = (unsigned)(ln + 32);
    const int blk = blockIdx.x, b = blk >> 7, sp = blk & (BPB - 1);

    if (t < K) s_cnt[t] = 0;
    __syncthreads();

    // ids for this span from k0's id8 (1 word = 4 pts per thread)
    {
        const size_t off = (size_t)b * NPTS + sp * SPAN + t * 4;
        const unsigned wrd = *(const unsigned*)(id8 + off);
        s_id4[t] = wrd;
#pragma unroll
        for (int j = 0; j < 4; ++j) {
            const unsigned e = (wrd >> (8 * j)) & 255u;
            if (e < 64u) atomicAdd(&s_cnt[e], 1);
        }
    }

    f32x16 acc0, acc1;
#pragma unroll
    for (int i = 0; i < 16; ++i) { acc0[i] = 0.f; acc1[i] = 0.f; }

    const unsigned* xb = (const unsigned*)(x + (size_t)b * D * NPTS + sp * SPAN);

    // prefetch subtile 0: wave w owns rows {w, 4+w, ..., 28+w}; 1KB contiguous per row
    uint4 pf[8];
#pragma unroll
    for (int P = 0; P < 8; ++P)
        pf[P] = *(const uint4*)(xb + (size_t)(P * 4 + w) * NPTS + L * 4);

    for (int st = 0; st < 4; ++st) {
        // ---- write prefetched tile -> LDS bf16, 16B-granule XOR swizzle
#pragma unroll
        for (int P = 0; P < 8; ++P) {
            const int row = P * 4 + w;
            const unsigned u0 = bfpack(pf[P].x + 0x8000u, pf[P].y + 0x8000u);
            const unsigned u1 = bfpack(pf[P].z + 0x8000u, pf[P].w + 0x8000u);
            const int waddr = row * 512 + (((L >> 1) ^ (row & 7)) * 16) + (L & 1) * 8;
            *(uint2*)(s_mem + waddr) = make_uint2(u0, u1);
        }
        if (st < 3) {                                  // prefetch next subtile
#pragma unroll
            for (int P = 0; P < 8; ++P)
                pf[P] = *(const uint4*)(xb + (size_t)(P * 4 + w) * NPTS
                                        + (st + 1) * 256 + L * 4);
        }
        __syncthreads();

        // ---- 4 chunks of 16 pts per wave
#pragma unroll
        for (int cc = 0; cc < 4; ++cc) {
            const int K16 = (w * 4 + cc) * 2 + g;      // 16B granule 0..31
            const int raddr = ln * 512 + ((K16 ^ (ln & 7)) * 16);
            const bf16x8 Af = *(const bf16x8*)(s_mem + raddr);

            const int n0 = st * 256 + (w * 4 + cc) * 16 + g * 8;
            const uint2 idq = *(const uint2*)(&s_id4[n0 >> 2]);
            union { unsigned u[4]; bf16x8 v; } B0, B1;
#pragma unroll
            for (int p = 0; p < 4; ++p) {
                const unsigned pair = ((p < 2) ? idq.x : idq.y) >> ((p & 1) * 16);
                const unsigned e0 = pair & 255u, e1 = (pair >> 8) & 255u;
                unsigned r0 = (e0 == lnu)   ? 0x3F80u : 0u;
                unsigned r1 = (e0 == lnp32) ? 0x3F80u : 0u;
                if (e1 == lnu)   r0 |= 0x3F800000u;
                if (e1 == lnp32) r1 |= 0x3F800000u;
                B0.u[p] = r0; B1.u[p] = r1;
            }
            acc0 = __builtin_amdgcn_mfma_f32_32x32x16_bf16(Af, B0.v, acc0, 0, 0, 0);
            acc1 = __builtin_amdgcn_mfma_f32_32x32x16_bf16(Af, B1.v, acc1, 0, 0, 0);
        }
        __syncthreads();
    }

    // ---- epilogue: combine 4 waves in LDS (reuse s_mem), atomics into musum
    float (*s_part)[2048] = (float(*)[2048])s_mem;
#pragma unroll
    for (int r = 0; r < 16; ++r) {
        const int row = (r & 3) + 8 * (r >> 2) + 4 * g;   // d
        s_part[w][row * 64 + ln]      = acc0[r];          // k = ln
        s_part[w][row * 64 + ln + 32] = acc1[r];          // k = ln+32
    }
    __syncthreads();

    float* dst = musum + (size_t)b * 2048;                // layout [d][k]
    for (int i = t; i < 2048; i += 256)
        unsafeAtomicAdd(&dst[i],
            s_part[0][i] + s_part[1][i] + s_part[2][i] + s_part[3][i]);
    if (t < K) {
        const int c = s_cnt[t];
        if (c) atomicAdd(&cnt[b * K + t], c);
    }
}

// ---------------------------------------------------------------- K3: variance via LDS gather
// mu staged in LDS (8KB, [d][k]); 4 pts/lane; ds_read addr = q*4 + imm(d*256);
// max 2-way bank aliasing (q vs q+32). One LDS-atomic wave-op per 64 pts.
__global__ __launch_bounds__(256) void k3_var(
    const float* __restrict__ x, const uchar* __restrict__ id8,
    const float* __restrict__ musum, const int* __restrict__ cnt,
    float* __restrict__ vsum)
{
    __shared__ float s_mu[2048];
    __shared__ float s_var[K];
    const int t = threadIdx.x;
    const int blk = blockIdx.x, b = blk >> 7, sp = blk & (BPB - 1);

    if (t < K) s_var[t] = 0.f;
    for (int i = t; i < 2048; i += 256)
        s_mu[i] = musum[(size_t)b * 2048 + i]
                / ((float)cnt[b * K + (i & 63)] + 1e-8f);

    const unsigned idw = *(const unsigned*)(id8 + (size_t)b * NPTS + sp * SPAN + t * 4);
    int q[4]; bool val[4];
#pragma unroll
    for (int j = 0; j < 4; ++j) {
        const unsigned e = (idw >> (8 * j)) & 255u;
        val[j] = (e < 64u);
        q[j] = (int)(e & 63u);          // clamped LDS index for invalid pts
    }
    __syncthreads();

    const float* xp = x + (size_t)b * D * NPTS + sp * SPAN + t * 4;
    float s0 = 0.f, s1 = 0.f, s2 = 0.f, s3 = 0.f;
#pragma unroll
    for (int d = 0; d < D; ++d) {
        const float4 xv = *(const float4*)(xp + (size_t)d * NPTS);
        s0 += fabsf(xv.x - s_mu[d * 64 + q[0]]);
        s1 += fabsf(xv.y - s_mu[d * 64 + q[1]]);
        s2 += fabsf(xv.z - s_mu[d * 64 + q[2]]);
        s3 += fabsf(xv.w - s_mu[d * 64 + q[3]]);
    }

    const float ss[4] = {s0, s1, s2, s3};
#pragma unroll
    for (int j = 0; j < 4; ++j) {
        if (val[j]) {
            const float h = fmaxf(ss[j] - DELTA_V, 0.f);
            if (h > 0.f) unsafeAtomicAdd(&s_var[q[j]], h * h);
        }
    }
    __syncthreads();
    if (t < K) {
        const float v = s_var[t];
        if (v != 0.f) unsafeAtomicAdd(&vsum[b * K + t], v);
    }
}

// ---------------------------------------------------------------- K4: finalize (8 blocks, one per batch)
__device__ float block_reduce_sum512(float v, float* s_buf) {
    for (int o = 32; o > 0; o >>= 1) v += __shfl_down(v, o, 64);
    const int wid  = threadIdx.x >> 6;
    const int lane = threadIdx.x & 63;
    if (lane == 0) s_buf[wid] = v;
    __syncthreads();
    float r = 0.f;
    if (threadIdx.x == 0)
        for (int w = 0; w < 8; ++w) r += s_buf[w];
    __syncthreads();
    return r;
}

__global__ __launch_bounds__(512) void k4_final(const float* __restrict__ musum,
                                                const int* __restrict__ cnt,
                                                const float* __restrict__ vsum,
                                                float* __restrict__ out)
{
    const int b = blockIdx.x;
    __shared__ float s_mu[K][D + 1];
    __shared__ float s_cnt[K];
    __shared__ float s_red[8];

    const int t = threadIdx.x;
    if (t < K) s_cnt[t] = (float)cnt[b * K + t];
    for (int i = t; i < K * D; i += 512) {           // musum [d][k] -> s_mu[k][d]
        const int d = i >> 6, k = i & 63;
        s_mu[k][d] = musum[(size_t)b * 2048 + i]
                   / ((float)cnt[b * K + k] + 1e-8f);
    }
    __syncthreads();

    float distPart = 0.f;
    for (int p = t; p < K * K; p += 512) {
        const int i = p >> 6, j = p & 63;
        if (i != j && s_cnt[i] > 0.f && s_cnt[j] > 0.f) {
            float dsum = 0.f;
#pragma unroll
            for (int d = 0; d < D; ++d) dsum += fabsf(s_mu[i][d] - s_mu[j][d]);
            const float h = fmaxf(TWO_DELTA_D - dsum, 0.f);
            distPart += h * h;
        }
    }
    float regPart = 0.f;
    for (int i = t; i < K * D; i += 512) {
        const int k = i >> 5;
        if (s_cnt[k] > 0.f) regPart += fabsf(s_mu[k][i & 31]);
    }
    float varPart = 0.f, npPart = 0.f;
    if (t < K) {
        varPart = vsum[b * K + t] / (s_cnt[t] + 1e-8f);
        npPart  = (s_cnt[t] > 0.f) ? 1.f : 0.f;
    }

    const float distSum = block_reduce_sum512(distPart, s_red);
    const float regSum  = block_reduce_sum512(regPart,  s_red);
    const float varSum  = block_reduce_sum512(varPart,  s_red);
    const float npSum   = block_reduce_sum512(npPart,   s_red);

    if (t == 0) {
        const float n_inst = fmaxf(npSum, 1.0f);
        const float npairs = npSum * npSum - npSum;
        const float l_var  = varSum / n_inst;
        const float l_dist = (npairs > 0.f) ? (distSum / fmaxf(npairs, 1.0f)) : 0.f;
        const float l_reg  = PARAM_REG * (regSum / n_inst);
        const float invB   = 1.0f / (float)B;
        unsafeAtomicAdd(out + 0, (l_var + l_dist + l_reg) * invB);
        unsafeAtomicAdd(out + 1, l_var  * invB);
        unsafeAtomicAdd(out + 2, l_dist * invB);
        unsafeAtomicAdd(out + 3, l_reg  * invB);
    }
}

// ---------------------------------------------------------------- launch
extern "C" void kernel_launch(void* const* d_in, const int* in_sizes, int n_in,
                              void* d_out, int out_size, void* d_ws, size_t ws_size,
                              hipStream_t stream) {
    const float* x    = (const float*)d_in[0];
    const int*   sem  = (const int*)d_in[1];
    const int*   inst = (const int*)d_in[2];
    float*       out  = (float*)d_out;
    float*       ws   = (float*)d_ws;

    float* musum = ws;
    int*   cnt   = (int*)(ws + OFF_CNT);
    float* vsum  = ws + OFF_VS;
    uchar* id8   = (uchar*)(ws + OFF_ID);

    k0_ids  <<<dim3(B * NPTS / 2048), dim3(256), 0, stream>>>(sem, inst, id8, ws, out);
    k1_fused<<<dim3(B * BPB), dim3(256), 0, stream>>>(x, id8, cnt, musum);
    k3_var  <<<dim3(B * BPB), dim3(256), 0, stream>>>(x, id8, musum, cnt, vsum);
    k4_final<<<dim3(B), dim3(512), 0, stream>>>(musum, cnt, vsum, out);
}